// Round 1
// 181.459 us; speedup vs baseline: 1.0670x; 1.0670x over previous
//
#include <hip/hip_runtime.h>
#include <hip/hip_bf16.h>

// CausalGraphLayer: out = [D^-1/2 (A+I) D^-1/2 (x W) + b] @ softmax(CA)
// Folded: M = W @ softmax(CA); bs = b @ softmax(CA);
//         z[i] = dinv[i] * (x[i] @ M)   (stored bf16)
//         out[d] = dinv[d] * (z[d] + sum_{(s,d) in E} z[s]) + bs
// N = 100000, E = 1600000, D = 64.
//
// Round 13: split rebin_zmat (49us, 22% occupancy, grid-starved at 782
// blocks + LDS-issue-bound z phase) into:
//   sort_kernel : 64-node buckets (grid 1563, 6 blk/CU), wave-shfl scan
//                 (3 barriers instead of ~16).
//   zmat_kernel : dedicated x@M GEMM, 4x4 register micro-tile, float4
//                 k-chunks (2 B LDS / FMA vs 20 B / 4 FMA). Same k
//                 accumulation order -> bit-identical z.
// bin v3 keeps BIN_TILE=8192; only histogram widened to 2048 buckets.
// gather = round-10/11 proven, verbatim.

#define D 64
#define BSHIFT 6
#define BNODES 64        // nodes per bucket
#define ARENA_CAP 1728   // arena slots per bucket (mean 1024, +22 sigma)
#define BIN_TILE 8192    // bin edges per block (196 blocks)

// f32 -> bf16 (round to nearest even)
__device__ __forceinline__ unsigned short f2bf(float f) {
    union { float f; unsigned int u; } c;
    c.f = f;
    unsigned int u = c.u;
    u += 0x7fffu + ((u >> 16) & 1u);
    return (unsigned short)(u >> 16);
}
// low/high bf16 of a packed uint -> f32
__device__ __forceinline__ float bflo(unsigned int u) {
    union { unsigned int u; float f; } c;
    c.u = u << 16;
    return c.f;
}
__device__ __forceinline__ float bfhi(unsigned int u) {
    union { unsigned int u; float f; } c;
    c.u = u & 0xffff0000u;
    return c.f;
}

// ---------------- K1: prep v2 — S = softmax(A); M = W@S; bs = b@S -----------
// 4 waves x 16 rows: lane j holds A[r][j]; max/sum via shfl_xor butterflies.
__global__ __launch_bounds__(256) void prep_kernel(const float* __restrict__ W,
                                                   const float* __restrict__ b,
                                                   const float* __restrict__ A,
                                                   float* __restrict__ M,
                                                   float* __restrict__ bs,
                                                   int* __restrict__ cursor, int nbuck) {
    __shared__ float S[D * D];
    int t = threadIdx.x;
    int gidx = blockIdx.x * 256 + t;
    if (gidx < nbuck) cursor[gidx] = gidx * ARENA_CAP;  // arena base
    int wv = t >> 6, lane = t & 63;
#pragma unroll 4
    for (int rr = 0; rr < 16; rr++) {
        int r = wv * 16 + rr;
        float a = A[r * D + lane];
        float m = a;
        for (int off = 32; off; off >>= 1) m = fmaxf(m, __shfl_xor(m, off));
        float p = __expf(a - m);
        float ssum = p;
        for (int off = 32; off; off >>= 1) ssum += __shfl_xor(ssum, off);
        S[r * D + lane] = p / ssum;
    }
    __syncthreads();
    int k = blockIdx.x * 4 + wv;  // M row (wave-uniform)
    float acc = 0.f;
    for (int d2 = 0; d2 < D; d2++) acc += W[k * D + d2] * S[d2 * D + lane];
    M[k * D + lane] = acc;
    if (blockIdx.x == 0 && t < D) {
        float a2 = 0.f;
        for (int d2 = 0; d2 < D; d2++) a2 += b[d2] * S[d2 * D + t];
        bs[t] = a2;
    }
}

// ---------------- K2: bin v3 — register staging, 16 edges/thread ------------
__global__ __launch_bounds__(512) void bin_kernel(const int* __restrict__ src,
                                                  const int* __restrict__ dst,
                                                  int* __restrict__ cursor,
                                                  int* __restrict__ binned, int E) {
    __shared__ int h[2048];
    int t = threadIdx.x;
    for (int i = t; i < 2048; i += 512) h[i] = 0;
    __syncthreads();
    int base = blockIdx.x * BIN_TILE;
    int pv[16], bk[16], rv[16];
#pragma unroll
    for (int k = 0; k < 16; k++) {
        int e = base + k * 512 + t;
        if (e < E) {
            int s = src[e], d = dst[e];
            bk[k] = (d >> BSHIFT) & 2047;
            pv[k] = (s << BSHIFT) | (d & (BNODES - 1));  // packed: src<<6 | dlocal
            rv[k] = atomicAdd(&h[bk[k]], 1);             // rank within (block,bucket)
        }
    }
    __syncthreads();
    for (int b2 = t; b2 < 2048; b2 += 512) {
        int c = h[b2];
        if (c) h[b2] = atomicAdd(&cursor[b2], c);  // h[b2] := global write base
    }
    __syncthreads();
#pragma unroll
    for (int k = 0; k < 16; k++) {
        int e = base + k * 512 + t;
        if (e < E) binned[h[bk[k]] + rv[k]] = pv[k];
    }
}

// ---------------- K3: in-bucket sort (64-node buckets, wave-shfl scan) ------
__global__ __launch_bounds__(256) void sort_kernel(int* __restrict__ binned,
                                                   const int* __restrict__ cursor,
                                                   int* __restrict__ rowstart,
                                                   int* __restrict__ rowend,
                                                   float* __restrict__ dinv,
                                                   int N) {
    __shared__ int buf[ARENA_CAP];   // 6.9 KB
    __shared__ int h[BNODES];
    __shared__ int cur[BNODES];
    int t = threadIdx.x;
    int b = blockIdx.x;
    int s = b * ARENA_CAP;
    int cnt = cursor[b] - s;
    if (cnt > ARENA_CAP) cnt = ARENA_CAP;  // by construction never binds
    if (t < BNODES) h[t] = 0;
    __syncthreads();
    for (int i = t; i < cnt; i += 256) {
        int p = binned[s + i];
        buf[i] = p;
        atomicAdd(&h[p & (BNODES - 1)], 1);
    }
    __syncthreads();
    if (t < BNODES) {  // threads 0..63 == wave 0: shfl inclusive scan
        int v = h[t];
        int sc = v;
#pragma unroll
        for (int off = 1; off < BNODES; off <<= 1) {
            int u = __shfl_up(sc, off);
            if (t >= off) sc += u;
        }
        cur[t] = sc - v;  // exclusive prefix
        int node = (b << BSHIFT) + t;
        if (node < N) {
            rowstart[node] = s + sc - v;
            rowend[node] = s + sc;
            dinv[node] = rsqrtf((float)(v + 1));
        }
    }
    __syncthreads();
    for (int i = t; i < cnt; i += 256) {
        int p = buf[i];
        int pos = atomicAdd(&cur[p & (BNODES - 1)], 1);
        binned[s + pos] = (int)((unsigned)p >> BSHIFT);  // plain src index
    }
}

// ---------------- K4: z = dinv * (x @ M), bf16 out --------------------------
// 64 rows/block, 256 threads, 4x4 register micro-tile, float4 k-chunks.
// Accumulation order over k identical to previous fused kernel -> z bit-equal.
__device__ __forceinline__ void fma4(float4& a, float xv, const float4& m) {
    a.x += xv * m.x; a.y += xv * m.y; a.z += xv * m.z; a.w += xv * m.w;
}
__global__ __launch_bounds__(256) void zmat_kernel(const float* __restrict__ x,
                                                   const float* __restrict__ M,
                                                   const float* __restrict__ dinv,
                                                   unsigned short* __restrict__ zbf,
                                                   int N) {
    __shared__ float Ms[D * D];      // 16 KB
    __shared__ float xs[64][D + 4];  // 17 KB (pad 4: bank spread + 16B align)
    int t = threadIdx.x;
    int row0 = blockIdx.x << 6;
    for (int i = t; i < (D * D) / 4; i += 256)
        ((float4*)Ms)[i] = ((const float4*)M)[i];
    for (int w = t; w < 1024; w += 256) {
        int r = w >> 4, c4 = (w & 15) << 2;
        int row = row0 + r;
        float4 v = make_float4(0.f, 0.f, 0.f, 0.f);
        if (row < N) v = *(const float4*)&x[(size_t)row * D + c4];
        *(float4*)&xs[r][c4] = v;
    }
    __syncthreads();
    int cg = t & 15, rg = t >> 4;
    int r0 = rg << 2, c0 = cg << 2;
    float4 a0 = make_float4(0.f, 0.f, 0.f, 0.f);
    float4 a1 = a0, a2 = a0, a3 = a0;
#pragma unroll 4
    for (int k = 0; k < D; k += 4) {
        float4 x0 = *(const float4*)&xs[r0 + 0][k];
        float4 x1 = *(const float4*)&xs[r0 + 1][k];
        float4 x2 = *(const float4*)&xs[r0 + 2][k];
        float4 x3 = *(const float4*)&xs[r0 + 3][k];
        float4 m0 = *(const float4*)&Ms[(k + 0) * D + c0];
        float4 m1 = *(const float4*)&Ms[(k + 1) * D + c0];
        float4 m2 = *(const float4*)&Ms[(k + 2) * D + c0];
        float4 m3 = *(const float4*)&Ms[(k + 3) * D + c0];
        fma4(a0, x0.x, m0); fma4(a0, x0.y, m1); fma4(a0, x0.z, m2); fma4(a0, x0.w, m3);
        fma4(a1, x1.x, m0); fma4(a1, x1.y, m1); fma4(a1, x1.z, m2); fma4(a1, x1.w, m3);
        fma4(a2, x2.x, m0); fma4(a2, x2.y, m1); fma4(a2, x2.z, m2); fma4(a2, x2.w, m3);
        fma4(a3, x3.x, m0); fma4(a3, x3.y, m1); fma4(a3, x3.z, m2); fma4(a3, x3.w, m3);
    }
    int rowb = row0 + r0;
    if (rowb < N) {  // N % 4 == 0: all 4 rows valid together
        float4 dv4 = *(const float4*)&dinv[rowb];
        ushort4 s0, s1, s2, s3;
        s0.x = f2bf(dv4.x * a0.x); s0.y = f2bf(dv4.x * a0.y);
        s0.z = f2bf(dv4.x * a0.z); s0.w = f2bf(dv4.x * a0.w);
        s1.x = f2bf(dv4.y * a1.x); s1.y = f2bf(dv4.y * a1.y);
        s1.z = f2bf(dv4.y * a1.z); s1.w = f2bf(dv4.y * a1.w);
        s2.x = f2bf(dv4.z * a2.x); s2.y = f2bf(dv4.z * a2.y);
        s2.z = f2bf(dv4.z * a2.z); s2.w = f2bf(dv4.z * a2.w);
        s3.x = f2bf(dv4.w * a3.x); s3.y = f2bf(dv4.w * a3.y);
        s3.z = f2bf(dv4.w * a3.z); s3.w = f2bf(dv4.w * a3.w);
        *(ushort4*)&zbf[(size_t)(rowb + 0) * D + c0] = s0;
        *(ushort4*)&zbf[(size_t)(rowb + 1) * D + c0] = s1;
        *(ushort4*)&zbf[(size_t)(rowb + 2) * D + c0] = s2;
        *(ushort4*)&zbf[(size_t)(rowb + 3) * D + c0] = s3;
    }
}

// ---------------- K5: gather v3 (round-10/11 proven, verbatim) --------------
__global__ __launch_bounds__(256) void gather_kernel(const unsigned short* __restrict__ zbf,
                                                     const int* __restrict__ csr,
                                                     const int* __restrict__ rowstart,
                                                     const int* __restrict__ rowend,
                                                     const float* __restrict__ dinv,
                                                     const float* __restrict__ bs,
                                                     float* __restrict__ out, int n) {
    int node = blockIdx.x * 4 + (threadIdx.x >> 6);
    if (node >= n) return;
    int lane = threadIdx.x & 63;
    int g = lane >> 5;
    int c = lane & 31;
    int start = rowstart[node];
    int end = rowend[node];
    float a0 = 0.f, a1 = 0.f, a2 = 0.f, a3 = 0.f;
    int e = start;
    while (e < end) {
        int cnt = min(end - e, 64);
        int sreg = (lane < cnt) ? csr[e + lane] : 0;
        int k = 0;
        for (; k + 7 < cnt; k += 8) {  // 8 edges / iter, 4 loads in flight
            int p0 = __shfl(sreg, k + g);
            int p1 = __shfl(sreg, k + 2 + g);
            int p2 = __shfl(sreg, k + 4 + g);
            int p3 = __shfl(sreg, k + 6 + g);
            unsigned u0 = *(const unsigned*)&zbf[(size_t)p0 * D + 2 * c];
            unsigned u1 = *(const unsigned*)&zbf[(size_t)p1 * D + 2 * c];
            unsigned u2 = *(const unsigned*)&zbf[(size_t)p2 * D + 2 * c];
            unsigned u3 = *(const unsigned*)&zbf[(size_t)p3 * D + 2 * c];
            a0 += bflo(u0); a1 += bfhi(u0);
            a2 += bflo(u1); a3 += bfhi(u1);
            a0 += bflo(u2); a1 += bfhi(u2);
            a2 += bflo(u3); a3 += bfhi(u3);
        }
        for (; k + 1 < cnt; k += 2) {  // pair tail
            int p = __shfl(sreg, k + g);
            unsigned u = *(const unsigned*)&zbf[(size_t)p * D + 2 * c];
            a0 += bflo(u); a1 += bfhi(u);
        }
        if (k < cnt) {  // odd last edge
            int p = __shfl(sreg, k);
            unsigned u = *(const unsigned*)&zbf[(size_t)p * D + 2 * c];
            if (g == 0) { a0 += bflo(u); a1 += bfhi(u); }
        }
        e += cnt;
    }
    a0 += a2; a1 += a3;
    a0 += __shfl_xor(a0, 32);  // merge g halves
    a1 += __shfl_xor(a1, 32);
    if (lane < 32) {
        unsigned uz = *(const unsigned*)&zbf[(size_t)node * D + 2 * c];  // self loop
        float2 bb = ((const float2*)bs)[c];
        float di = dinv[node];
        float2 o;
        o.x = di * (a0 + bflo(uz)) + bb.x;
        o.y = di * (a1 + bfhi(uz)) + bb.y;
        ((float2*)&out[(size_t)node * D])[c] = o;
    }
}

extern "C" void kernel_launch(void* const* d_in, const int* in_sizes, int n_in,
                              void* d_out, int out_size, void* d_ws, size_t ws_size,
                              hipStream_t stream) {
    const float* x = (const float*)d_in[0];
    const int* ei = (const int*)d_in[1];
    const float* W = (const float*)d_in[2];
    const float* b = (const float*)d_in[3];
    const float* A = (const float*)d_in[4];

    const int N = in_sizes[0] / D;
    const int E = in_sizes[1] / 2;
    const int* src = ei;
    const int* dst = ei + E;
    const int NBUCK = (N + BNODES - 1) >> BSHIFT;  // 1563; must be <=2048

    char* ws = (char*)d_ws;
    size_t off = 0;
    auto alloc = [&](size_t bytes) -> char* {
        char* p = ws + off;
        off = (off + bytes + 255) & ~(size_t)255;
        return p;
    };
    int* cursor = (int*)alloc((size_t)NBUCK * 4);
    float* dinv = (float*)alloc((size_t)N * 4);
    float* M = (float*)alloc((size_t)D * D * 4);
    float* bs = (float*)alloc((size_t)D * 4);
    int* binned = (int*)alloc((size_t)NBUCK * ARENA_CAP * 4);  // 10.8 MB arena
    int* rowstart = (int*)alloc((size_t)N * 4);
    int* rowend = (int*)alloc((size_t)N * 4);
    unsigned short* zbf = (unsigned short*)alloc((size_t)N * D * 2);
    (void)ws_size;  // total ~25 MiB (< 32.06 MiB proven safe)

    prep_kernel<<<16, 256, 0, stream>>>(W, b, A, M, bs, cursor, NBUCK);
    bin_kernel<<<(E + BIN_TILE - 1) / BIN_TILE, 512, 0, stream>>>(src, dst, cursor, binned, E);
    sort_kernel<<<NBUCK, 256, 0, stream>>>(binned, cursor, rowstart, rowend, dinv, N);
    zmat_kernel<<<(N + 63) >> 6, 256, 0, stream>>>(x, M, dinv, zbf, N);
    gather_kernel<<<(N + 3) / 4, 256, 0, stream>>>(zbf, binned, rowstart, rowend, dinv, bs, (float*)d_out, N);
}

// Round 2
// 176.165 us; speedup vs baseline: 1.0991x; 1.0300x over previous
//
#include <hip/hip_runtime.h>
#include <hip/hip_bf16.h>

// CausalGraphLayer: out = [D^-1/2 (A+I) D^-1/2 (x W) + b] @ softmax(CA)
// Folded: M = W @ softmax(CA); bs = b @ softmax(CA);
//         z[i] = dinv[i] * (x[i] @ M)   (stored bf16)
//         out[d] = dinv[d] * (z[d] + sum_{(s,d) in E} z[s]) + bs
// N = 100000, E = 1600000, D = 64.
//
// Round 14: gather v4 — latency-bound random gather (46us, 32% HBM, 40%
// VALU). Raise memory-level parallelism: 16-edge chunks with 8 loads in
// flight (was 4), plus hoist self-loop/dinv/bs loads ahead of the edge
// loop so their latency overlaps the gather. Everything else verbatim
// from round 13 (prep v2 / bin v3 / sort / zmat 4x4).

#define D 64
#define BSHIFT 6
#define BNODES 64        // nodes per bucket
#define ARENA_CAP 1728   // arena slots per bucket (mean 1024, +22 sigma)
#define BIN_TILE 8192    // bin edges per block (196 blocks)

// f32 -> bf16 (round to nearest even)
__device__ __forceinline__ unsigned short f2bf(float f) {
    union { float f; unsigned int u; } c;
    c.f = f;
    unsigned int u = c.u;
    u += 0x7fffu + ((u >> 16) & 1u);
    return (unsigned short)(u >> 16);
}
// low/high bf16 of a packed uint -> f32
__device__ __forceinline__ float bflo(unsigned int u) {
    union { unsigned int u; float f; } c;
    c.u = u << 16;
    return c.f;
}
__device__ __forceinline__ float bfhi(unsigned int u) {
    union { unsigned int u; float f; } c;
    c.u = u & 0xffff0000u;
    return c.f;
}

// ---------------- K1: prep v2 — S = softmax(A); M = W@S; bs = b@S -----------
// 4 waves x 16 rows: lane j holds A[r][j]; max/sum via shfl_xor butterflies.
__global__ __launch_bounds__(256) void prep_kernel(const float* __restrict__ W,
                                                   const float* __restrict__ b,
                                                   const float* __restrict__ A,
                                                   float* __restrict__ M,
                                                   float* __restrict__ bs,
                                                   int* __restrict__ cursor, int nbuck) {
    __shared__ float S[D * D];
    int t = threadIdx.x;
    int gidx = blockIdx.x * 256 + t;
    if (gidx < nbuck) cursor[gidx] = gidx * ARENA_CAP;  // arena base
    int wv = t >> 6, lane = t & 63;
#pragma unroll 4
    for (int rr = 0; rr < 16; rr++) {
        int r = wv * 16 + rr;
        float a = A[r * D + lane];
        float m = a;
        for (int off = 32; off; off >>= 1) m = fmaxf(m, __shfl_xor(m, off));
        float p = __expf(a - m);
        float ssum = p;
        for (int off = 32; off; off >>= 1) ssum += __shfl_xor(ssum, off);
        S[r * D + lane] = p / ssum;
    }
    __syncthreads();
    int k = blockIdx.x * 4 + wv;  // M row (wave-uniform)
    float acc = 0.f;
    for (int d2 = 0; d2 < D; d2++) acc += W[k * D + d2] * S[d2 * D + lane];
    M[k * D + lane] = acc;
    if (blockIdx.x == 0 && t < D) {
        float a2 = 0.f;
        for (int d2 = 0; d2 < D; d2++) a2 += b[d2] * S[d2 * D + t];
        bs[t] = a2;
    }
}

// ---------------- K2: bin v3 — register staging, 16 edges/thread ------------
__global__ __launch_bounds__(512) void bin_kernel(const int* __restrict__ src,
                                                  const int* __restrict__ dst,
                                                  int* __restrict__ cursor,
                                                  int* __restrict__ binned, int E) {
    __shared__ int h[2048];
    int t = threadIdx.x;
    for (int i = t; i < 2048; i += 512) h[i] = 0;
    __syncthreads();
    int base = blockIdx.x * BIN_TILE;
    int pv[16], bk[16], rv[16];
#pragma unroll
    for (int k = 0; k < 16; k++) {
        int e = base + k * 512 + t;
        if (e < E) {
            int s = src[e], d = dst[e];
            bk[k] = (d >> BSHIFT) & 2047;
            pv[k] = (s << BSHIFT) | (d & (BNODES - 1));  // packed: src<<6 | dlocal
            rv[k] = atomicAdd(&h[bk[k]], 1);             // rank within (block,bucket)
        }
    }
    __syncthreads();
    for (int b2 = t; b2 < 2048; b2 += 512) {
        int c = h[b2];
        if (c) h[b2] = atomicAdd(&cursor[b2], c);  // h[b2] := global write base
    }
    __syncthreads();
#pragma unroll
    for (int k = 0; k < 16; k++) {
        int e = base + k * 512 + t;
        if (e < E) binned[h[bk[k]] + rv[k]] = pv[k];
    }
}

// ---------------- K3: in-bucket sort (64-node buckets, wave-shfl scan) ------
__global__ __launch_bounds__(256) void sort_kernel(int* __restrict__ binned,
                                                   const int* __restrict__ cursor,
                                                   int* __restrict__ rowstart,
                                                   int* __restrict__ rowend,
                                                   float* __restrict__ dinv,
                                                   int N) {
    __shared__ int buf[ARENA_CAP];   // 6.9 KB
    __shared__ int h[BNODES];
    __shared__ int cur[BNODES];
    int t = threadIdx.x;
    int b = blockIdx.x;
    int s = b * ARENA_CAP;
    int cnt = cursor[b] - s;
    if (cnt > ARENA_CAP) cnt = ARENA_CAP;  // by construction never binds
    if (t < BNODES) h[t] = 0;
    __syncthreads();
    for (int i = t; i < cnt; i += 256) {
        int p = binned[s + i];
        buf[i] = p;
        atomicAdd(&h[p & (BNODES - 1)], 1);
    }
    __syncthreads();
    if (t < BNODES) {  // threads 0..63 == wave 0: shfl inclusive scan
        int v = h[t];
        int sc = v;
#pragma unroll
        for (int off = 1; off < BNODES; off <<= 1) {
            int u = __shfl_up(sc, off);
            if (t >= off) sc += u;
        }
        cur[t] = sc - v;  // exclusive prefix
        int node = (b << BSHIFT) + t;
        if (node < N) {
            rowstart[node] = s + sc - v;
            rowend[node] = s + sc;
            dinv[node] = rsqrtf((float)(v + 1));
        }
    }
    __syncthreads();
    for (int i = t; i < cnt; i += 256) {
        int p = buf[i];
        int pos = atomicAdd(&cur[p & (BNODES - 1)], 1);
        binned[s + pos] = (int)((unsigned)p >> BSHIFT);  // plain src index
    }
}

// ---------------- K4: z = dinv * (x @ M), bf16 out --------------------------
// 64 rows/block, 256 threads, 4x4 register micro-tile, float4 k-chunks.
// Accumulation order over k identical to previous fused kernel -> z bit-equal.
__device__ __forceinline__ void fma4(float4& a, float xv, const float4& m) {
    a.x += xv * m.x; a.y += xv * m.y; a.z += xv * m.z; a.w += xv * m.w;
}
__global__ __launch_bounds__(256) void zmat_kernel(const float* __restrict__ x,
                                                   const float* __restrict__ M,
                                                   const float* __restrict__ dinv,
                                                   unsigned short* __restrict__ zbf,
                                                   int N) {
    __shared__ float Ms[D * D];      // 16 KB
    __shared__ float xs[64][D + 4];  // 17 KB (pad 4: bank spread + 16B align)
    int t = threadIdx.x;
    int row0 = blockIdx.x << 6;
    for (int i = t; i < (D * D) / 4; i += 256)
        ((float4*)Ms)[i] = ((const float4*)M)[i];
    for (int w = t; w < 1024; w += 256) {
        int r = w >> 4, c4 = (w & 15) << 2;
        int row = row0 + r;
        float4 v = make_float4(0.f, 0.f, 0.f, 0.f);
        if (row < N) v = *(const float4*)&x[(size_t)row * D + c4];
        *(float4*)&xs[r][c4] = v;
    }
    __syncthreads();
    int cg = t & 15, rg = t >> 4;
    int r0 = rg << 2, c0 = cg << 2;
    float4 a0 = make_float4(0.f, 0.f, 0.f, 0.f);
    float4 a1 = a0, a2 = a0, a3 = a0;
#pragma unroll 4
    for (int k = 0; k < D; k += 4) {
        float4 x0 = *(const float4*)&xs[r0 + 0][k];
        float4 x1 = *(const float4*)&xs[r0 + 1][k];
        float4 x2 = *(const float4*)&xs[r0 + 2][k];
        float4 x3 = *(const float4*)&xs[r0 + 3][k];
        float4 m0 = *(const float4*)&Ms[(k + 0) * D + c0];
        float4 m1 = *(const float4*)&Ms[(k + 1) * D + c0];
        float4 m2 = *(const float4*)&Ms[(k + 2) * D + c0];
        float4 m3 = *(const float4*)&Ms[(k + 3) * D + c0];
        fma4(a0, x0.x, m0); fma4(a0, x0.y, m1); fma4(a0, x0.z, m2); fma4(a0, x0.w, m3);
        fma4(a1, x1.x, m0); fma4(a1, x1.y, m1); fma4(a1, x1.z, m2); fma4(a1, x1.w, m3);
        fma4(a2, x2.x, m0); fma4(a2, x2.y, m1); fma4(a2, x2.z, m2); fma4(a2, x2.w, m3);
        fma4(a3, x3.x, m0); fma4(a3, x3.y, m1); fma4(a3, x3.z, m2); fma4(a3, x3.w, m3);
    }
    int rowb = row0 + r0;
    if (rowb < N) {  // N % 4 == 0: all 4 rows valid together
        float4 dv4 = *(const float4*)&dinv[rowb];
        ushort4 s0, s1, s2, s3;
        s0.x = f2bf(dv4.x * a0.x); s0.y = f2bf(dv4.x * a0.y);
        s0.z = f2bf(dv4.x * a0.z); s0.w = f2bf(dv4.x * a0.w);
        s1.x = f2bf(dv4.y * a1.x); s1.y = f2bf(dv4.y * a1.y);
        s1.z = f2bf(dv4.y * a1.z); s1.w = f2bf(dv4.y * a1.w);
        s2.x = f2bf(dv4.z * a2.x); s2.y = f2bf(dv4.z * a2.y);
        s2.z = f2bf(dv4.z * a2.z); s2.w = f2bf(dv4.z * a2.w);
        s3.x = f2bf(dv4.w * a3.x); s3.y = f2bf(dv4.w * a3.y);
        s3.z = f2bf(dv4.w * a3.z); s3.w = f2bf(dv4.w * a3.w);
        *(ushort4*)&zbf[(size_t)(rowb + 0) * D + c0] = s0;
        *(ushort4*)&zbf[(size_t)(rowb + 1) * D + c0] = s1;
        *(ushort4*)&zbf[(size_t)(rowb + 2) * D + c0] = s2;
        *(ushort4*)&zbf[(size_t)(rowb + 3) * D + c0] = s3;
    }
}

// ---------------- K5: gather v4 — 8 loads in flight + hoisted epilogue ------
__global__ __launch_bounds__(256) void gather_kernel(const unsigned short* __restrict__ zbf,
                                                     const int* __restrict__ csr,
                                                     const int* __restrict__ rowstart,
                                                     const int* __restrict__ rowend,
                                                     const float* __restrict__ dinv,
                                                     const float* __restrict__ bs,
                                                     float* __restrict__ out, int n) {
    int node = blockIdx.x * 4 + (threadIdx.x >> 6);
    if (node >= n) return;
    int lane = threadIdx.x & 63;
    int g = lane >> 5;
    int c = lane & 31;
    int start = rowstart[node];
    int end = rowend[node];
    // hoisted epilogue loads: overlap their latency with the edge gather
    unsigned uz = *(const unsigned*)&zbf[(size_t)node * D + 2 * c];  // self loop
    float di = dinv[node];
    float2 bb = ((const float2*)bs)[c];
    float a0 = 0.f, a1 = 0.f, a2 = 0.f, a3 = 0.f;
    int e = start;
    while (e < end) {
        int cnt = min(end - e, 64);
        int sreg = (lane < cnt) ? csr[e + lane] : 0;
        int k = 0;
        for (; k + 15 < cnt; k += 16) {  // 16 edges / iter, 8 loads in flight
            int p0 = __shfl(sreg, k + g);
            int p1 = __shfl(sreg, k + 2 + g);
            int p2 = __shfl(sreg, k + 4 + g);
            int p3 = __shfl(sreg, k + 6 + g);
            int p4 = __shfl(sreg, k + 8 + g);
            int p5 = __shfl(sreg, k + 10 + g);
            int p6 = __shfl(sreg, k + 12 + g);
            int p7 = __shfl(sreg, k + 14 + g);
            unsigned u0 = *(const unsigned*)&zbf[(size_t)p0 * D + 2 * c];
            unsigned u1 = *(const unsigned*)&zbf[(size_t)p1 * D + 2 * c];
            unsigned u2 = *(const unsigned*)&zbf[(size_t)p2 * D + 2 * c];
            unsigned u3 = *(const unsigned*)&zbf[(size_t)p3 * D + 2 * c];
            unsigned u4 = *(const unsigned*)&zbf[(size_t)p4 * D + 2 * c];
            unsigned u5 = *(const unsigned*)&zbf[(size_t)p5 * D + 2 * c];
            unsigned u6 = *(const unsigned*)&zbf[(size_t)p6 * D + 2 * c];
            unsigned u7 = *(const unsigned*)&zbf[(size_t)p7 * D + 2 * c];
            a0 += bflo(u0); a1 += bfhi(u0);
            a2 += bflo(u1); a3 += bfhi(u1);
            a0 += bflo(u2); a1 += bfhi(u2);
            a2 += bflo(u3); a3 += bfhi(u3);
            a0 += bflo(u4); a1 += bfhi(u4);
            a2 += bflo(u5); a3 += bfhi(u5);
            a0 += bflo(u6); a1 += bfhi(u6);
            a2 += bflo(u7); a3 += bfhi(u7);
        }
        for (; k + 7 < cnt; k += 8) {  // 8 edges / iter, 4 loads in flight
            int p0 = __shfl(sreg, k + g);
            int p1 = __shfl(sreg, k + 2 + g);
            int p2 = __shfl(sreg, k + 4 + g);
            int p3 = __shfl(sreg, k + 6 + g);
            unsigned u0 = *(const unsigned*)&zbf[(size_t)p0 * D + 2 * c];
            unsigned u1 = *(const unsigned*)&zbf[(size_t)p1 * D + 2 * c];
            unsigned u2 = *(const unsigned*)&zbf[(size_t)p2 * D + 2 * c];
            unsigned u3 = *(const unsigned*)&zbf[(size_t)p3 * D + 2 * c];
            a0 += bflo(u0); a1 += bfhi(u0);
            a2 += bflo(u1); a3 += bfhi(u1);
            a0 += bflo(u2); a1 += bfhi(u2);
            a2 += bflo(u3); a3 += bfhi(u3);
        }
        for (; k + 1 < cnt; k += 2) {  // pair tail
            int p = __shfl(sreg, k + g);
            unsigned u = *(const unsigned*)&zbf[(size_t)p * D + 2 * c];
            a0 += bflo(u); a1 += bfhi(u);
        }
        if (k < cnt) {  // odd last edge
            int p = __shfl(sreg, k);
            unsigned u = *(const unsigned*)&zbf[(size_t)p * D + 2 * c];
            if (g == 0) { a0 += bflo(u); a1 += bfhi(u); }
        }
        e += cnt;
    }
    a0 += a2; a1 += a3;
    a0 += __shfl_xor(a0, 32);  // merge g halves
    a1 += __shfl_xor(a1, 32);
    if (lane < 32) {
        float2 o;
        o.x = di * (a0 + bflo(uz)) + bb.x;
        o.y = di * (a1 + bfhi(uz)) + bb.y;
        ((float2*)&out[(size_t)node * D])[c] = o;
    }
}

extern "C" void kernel_launch(void* const* d_in, const int* in_sizes, int n_in,
                              void* d_out, int out_size, void* d_ws, size_t ws_size,
                              hipStream_t stream) {
    const float* x = (const float*)d_in[0];
    const int* ei = (const int*)d_in[1];
    const float* W = (const float*)d_in[2];
    const float* b = (const float*)d_in[3];
    const float* A = (const float*)d_in[4];

    const int N = in_sizes[0] / D;
    const int E = in_sizes[1] / 2;
    const int* src = ei;
    const int* dst = ei + E;
    const int NBUCK = (N + BNODES - 1) >> BSHIFT;  // 1563; must be <=2048

    char* ws = (char*)d_ws;
    size_t off = 0;
    auto alloc = [&](size_t bytes) -> char* {
        char* p = ws + off;
        off = (off + bytes + 255) & ~(size_t)255;
        return p;
    };
    int* cursor = (int*)alloc((size_t)NBUCK * 4);
    float* dinv = (float*)alloc((size_t)N * 4);
    float* M = (float*)alloc((size_t)D * D * 4);
    float* bs = (float*)alloc((size_t)D * 4);
    int* binned = (int*)alloc((size_t)NBUCK * ARENA_CAP * 4);  // 10.8 MB arena
    int* rowstart = (int*)alloc((size_t)N * 4);
    int* rowend = (int*)alloc((size_t)N * 4);
    unsigned short* zbf = (unsigned short*)alloc((size_t)N * D * 2);
    (void)ws_size;  // total ~25 MiB (< 32.06 MiB proven safe)

    prep_kernel<<<16, 256, 0, stream>>>(W, b, A, M, bs, cursor, NBUCK);
    bin_kernel<<<(E + BIN_TILE - 1) / BIN_TILE, 512, 0, stream>>>(src, dst, cursor, binned, E);
    sort_kernel<<<NBUCK, 256, 0, stream>>>(binned, cursor, rowstart, rowend, dinv, N);
    zmat_kernel<<<(N + 63) >> 6, 256, 0, stream>>>(x, M, dinv, zbf, N);
    gather_kernel<<<(N + 3) / 4, 256, 0, stream>>>(zbf, binned, rowstart, rowend, dinv, bs, (float*)d_out, N);
}

// Round 4
// 171.818 us; speedup vs baseline: 1.1269x; 1.0253x over previous
//
#include <hip/hip_runtime.h>
#include <hip/hip_bf16.h>

// CausalGraphLayer: out = [D^-1/2 (A+I) D^-1/2 (x W) + b] @ softmax(CA)
// Folded: M = W @ softmax(CA); bs = b @ softmax(CA);
//         z[i] = dinv[i] * (x[i] @ M)   (stored bf16)
//         out[d] = dinv[d] * (z[d] + sum_{(s,d) in E} z[s]) + bs
// N = 100000, E = 1600000, D = 64.
//
// Round 16 (v5b): gather v5 fix. v5's tail did __shfl under divergent
// exec with an INACTIVE source lane (ds_bpermute from a disabled lane is
// undefined) -> garbage edge index for nodes with degree%4 != 0.
// Fix: uniform `if (r)` branch, shfl+load at full exec with clamped
// source lane, accumulate predicated. Pipeline/grouping unchanged:
// persistent waves, 2-stage cross-node prefetch, uint2 lanes (4 groups
// x 16 lanes). prep v2 / bin v3 / sort / zmat 4x4 verbatim.

#define D 64
#define BSHIFT 6
#define BNODES 64        // nodes per bucket
#define ARENA_CAP 1728   // arena slots per bucket (mean 1024, +22 sigma)
#define BIN_TILE 8192    // bin edges per block (196 blocks)

// f32 -> bf16 (round to nearest even)
__device__ __forceinline__ unsigned short f2bf(float f) {
    union { float f; unsigned int u; } c;
    c.f = f;
    unsigned int u = c.u;
    u += 0x7fffu + ((u >> 16) & 1u);
    return (unsigned short)(u >> 16);
}
// low/high bf16 of a packed uint -> f32
__device__ __forceinline__ float bflo(unsigned int u) {
    union { unsigned int u; float f; } c;
    c.u = u << 16;
    return c.f;
}
__device__ __forceinline__ float bfhi(unsigned int u) {
    union { unsigned int u; float f; } c;
    c.u = u & 0xffff0000u;
    return c.f;
}

// ---------------- K1: prep v2 — S = softmax(A); M = W@S; bs = b@S -----------
// 4 waves x 16 rows: lane j holds A[r][j]; max/sum via shfl_xor butterflies.
__global__ __launch_bounds__(256) void prep_kernel(const float* __restrict__ W,
                                                   const float* __restrict__ b,
                                                   const float* __restrict__ A,
                                                   float* __restrict__ M,
                                                   float* __restrict__ bs,
                                                   int* __restrict__ cursor, int nbuck) {
    __shared__ float S[D * D];
    int t = threadIdx.x;
    int gidx = blockIdx.x * 256 + t;
    if (gidx < nbuck) cursor[gidx] = gidx * ARENA_CAP;  // arena base
    int wv = t >> 6, lane = t & 63;
#pragma unroll 4
    for (int rr = 0; rr < 16; rr++) {
        int r = wv * 16 + rr;
        float a = A[r * D + lane];
        float m = a;
        for (int off = 32; off; off >>= 1) m = fmaxf(m, __shfl_xor(m, off));
        float p = __expf(a - m);
        float ssum = p;
        for (int off = 32; off; off >>= 1) ssum += __shfl_xor(ssum, off);
        S[r * D + lane] = p / ssum;
    }
    __syncthreads();
    int k = blockIdx.x * 4 + wv;  // M row (wave-uniform)
    float acc = 0.f;
    for (int d2 = 0; d2 < D; d2++) acc += W[k * D + d2] * S[d2 * D + lane];
    M[k * D + lane] = acc;
    if (blockIdx.x == 0 && t < D) {
        float a2 = 0.f;
        for (int d2 = 0; d2 < D; d2++) a2 += b[d2] * S[d2 * D + t];
        bs[t] = a2;
    }
}

// ---------------- K2: bin v3 — register staging, 16 edges/thread ------------
__global__ __launch_bounds__(512) void bin_kernel(const int* __restrict__ src,
                                                  const int* __restrict__ dst,
                                                  int* __restrict__ cursor,
                                                  int* __restrict__ binned, int E) {
    __shared__ int h[2048];
    int t = threadIdx.x;
    for (int i = t; i < 2048; i += 512) h[i] = 0;
    __syncthreads();
    int base = blockIdx.x * BIN_TILE;
    int pv[16], bk[16], rv[16];
#pragma unroll
    for (int k = 0; k < 16; k++) {
        int e = base + k * 512 + t;
        if (e < E) {
            int s = src[e], d = dst[e];
            bk[k] = (d >> BSHIFT) & 2047;
            pv[k] = (s << BSHIFT) | (d & (BNODES - 1));  // packed: src<<6 | dlocal
            rv[k] = atomicAdd(&h[bk[k]], 1);             // rank within (block,bucket)
        }
    }
    __syncthreads();
    for (int b2 = t; b2 < 2048; b2 += 512) {
        int c = h[b2];
        if (c) h[b2] = atomicAdd(&cursor[b2], c);  // h[b2] := global write base
    }
    __syncthreads();
#pragma unroll
    for (int k = 0; k < 16; k++) {
        int e = base + k * 512 + t;
        if (e < E) binned[h[bk[k]] + rv[k]] = pv[k];
    }
}

// ---------------- K3: in-bucket sort (64-node buckets, wave-shfl scan) ------
__global__ __launch_bounds__(256) void sort_kernel(int* __restrict__ binned,
                                                   const int* __restrict__ cursor,
                                                   int* __restrict__ rowstart,
                                                   int* __restrict__ rowend,
                                                   float* __restrict__ dinv,
                                                   int N) {
    __shared__ int buf[ARENA_CAP];   // 6.9 KB
    __shared__ int h[BNODES];
    __shared__ int cur[BNODES];
    int t = threadIdx.x;
    int b = blockIdx.x;
    int s = b * ARENA_CAP;
    int cnt = cursor[b] - s;
    if (cnt > ARENA_CAP) cnt = ARENA_CAP;  // by construction never binds
    if (t < BNODES) h[t] = 0;
    __syncthreads();
    for (int i = t; i < cnt; i += 256) {
        int p = binned[s + i];
        buf[i] = p;
        atomicAdd(&h[p & (BNODES - 1)], 1);
    }
    __syncthreads();
    if (t < BNODES) {  // threads 0..63 == wave 0: shfl inclusive scan
        int v = h[t];
        int sc = v;
#pragma unroll
        for (int off = 1; off < BNODES; off <<= 1) {
            int u = __shfl_up(sc, off);
            if (t >= off) sc += u;
        }
        cur[t] = sc - v;  // exclusive prefix
        int node = (b << BSHIFT) + t;
        if (node < N) {
            rowstart[node] = s + sc - v;
            rowend[node] = s + sc;
            dinv[node] = rsqrtf((float)(v + 1));
        }
    }
    __syncthreads();
    for (int i = t; i < cnt; i += 256) {
        int p = buf[i];
        int pos = atomicAdd(&cur[p & (BNODES - 1)], 1);
        binned[s + pos] = (int)((unsigned)p >> BSHIFT);  // plain src index
    }
}

// ---------------- K4: z = dinv * (x @ M), bf16 out --------------------------
// 64 rows/block, 256 threads, 4x4 register micro-tile, float4 k-chunks.
__device__ __forceinline__ void fma4(float4& a, float xv, const float4& m) {
    a.x += xv * m.x; a.y += xv * m.y; a.z += xv * m.z; a.w += xv * m.w;
}
__global__ __launch_bounds__(256) void zmat_kernel(const float* __restrict__ x,
                                                   const float* __restrict__ M,
                                                   const float* __restrict__ dinv,
                                                   unsigned short* __restrict__ zbf,
                                                   int N) {
    __shared__ float Ms[D * D];      // 16 KB
    __shared__ float xs[64][D + 4];  // 17 KB (pad 4: bank spread + 16B align)
    int t = threadIdx.x;
    int row0 = blockIdx.x << 6;
    for (int i = t; i < (D * D) / 4; i += 256)
        ((float4*)Ms)[i] = ((const float4*)M)[i];
    for (int w = t; w < 1024; w += 256) {
        int r = w >> 4, c4 = (w & 15) << 2;
        int row = row0 + r;
        float4 v = make_float4(0.f, 0.f, 0.f, 0.f);
        if (row < N) v = *(const float4*)&x[(size_t)row * D + c4];
        *(float4*)&xs[r][c4] = v;
    }
    __syncthreads();
    int cg = t & 15, rg = t >> 4;
    int r0 = rg << 2, c0 = cg << 2;
    float4 a0 = make_float4(0.f, 0.f, 0.f, 0.f);
    float4 a1 = a0, a2 = a0, a3 = a0;
#pragma unroll 4
    for (int k = 0; k < D; k += 4) {
        float4 x0 = *(const float4*)&xs[r0 + 0][k];
        float4 x1 = *(const float4*)&xs[r0 + 1][k];
        float4 x2 = *(const float4*)&xs[r0 + 2][k];
        float4 x3 = *(const float4*)&xs[r0 + 3][k];
        float4 m0 = *(const float4*)&Ms[(k + 0) * D + c0];
        float4 m1 = *(const float4*)&Ms[(k + 1) * D + c0];
        float4 m2 = *(const float4*)&Ms[(k + 2) * D + c0];
        float4 m3 = *(const float4*)&Ms[(k + 3) * D + c0];
        fma4(a0, x0.x, m0); fma4(a0, x0.y, m1); fma4(a0, x0.z, m2); fma4(a0, x0.w, m3);
        fma4(a1, x1.x, m0); fma4(a1, x1.y, m1); fma4(a1, x1.z, m2); fma4(a1, x1.w, m3);
        fma4(a2, x2.x, m0); fma4(a2, x2.y, m1); fma4(a2, x2.z, m2); fma4(a2, x2.w, m3);
        fma4(a3, x3.x, m0); fma4(a3, x3.y, m1); fma4(a3, x3.z, m2); fma4(a3, x3.w, m3);
    }
    int rowb = row0 + r0;
    if (rowb < N) {  // N % 4 == 0: all 4 rows valid together
        float4 dv4 = *(const float4*)&dinv[rowb];
        ushort4 s0, s1, s2, s3;
        s0.x = f2bf(dv4.x * a0.x); s0.y = f2bf(dv4.x * a0.y);
        s0.z = f2bf(dv4.x * a0.z); s0.w = f2bf(dv4.x * a0.w);
        s1.x = f2bf(dv4.y * a1.x); s1.y = f2bf(dv4.y * a1.y);
        s1.z = f2bf(dv4.y * a1.z); s1.w = f2bf(dv4.y * a1.w);
        s2.x = f2bf(dv4.z * a2.x); s2.y = f2bf(dv4.z * a2.y);
        s2.z = f2bf(dv4.z * a2.z); s2.w = f2bf(dv4.z * a2.w);
        s3.x = f2bf(dv4.w * a3.x); s3.y = f2bf(dv4.w * a3.y);
        s3.z = f2bf(dv4.w * a3.z); s3.w = f2bf(dv4.w * a3.w);
        *(ushort4*)&zbf[(size_t)(rowb + 0) * D + c0] = s0;
        *(ushort4*)&zbf[(size_t)(rowb + 1) * D + c0] = s1;
        *(ushort4*)&zbf[(size_t)(rowb + 2) * D + c0] = s2;
        *(ushort4*)&zbf[(size_t)(rowb + 3) * D + c0] = s3;
    }
}

// ---------------- K5: gather v5b — persistent, cross-node pipelined ---------
// Wave = 4 groups x 16 lanes; lane covers features [4*(lane&15) .. +3] (8 B).
// Each wave owns nodes wid, wid+stride, ... with a 2-stage pipeline:
// while node i is summed, node i+1's csr/self/dinv and node i+2's bounds
// are in flight. All __shfl calls execute at FULL exec (bpermute from an
// inactive source lane is undefined — the v5 bug); only accumulation is
// predicated in the tail.
__global__ __launch_bounds__(256) void gather_kernel(const unsigned short* __restrict__ zbf,
                                                     const int* __restrict__ csr,
                                                     const int* __restrict__ rowstart,
                                                     const int* __restrict__ rowend,
                                                     const float* __restrict__ dinv,
                                                     const float* __restrict__ bs,
                                                     float* __restrict__ out, int n) {
    int wid = blockIdx.x * 4 + (threadIdx.x >> 6);
    int lane = threadIdx.x & 63;
    int qg = lane >> 4;   // group 0..3
    int c4 = lane & 15;   // feature quad index
    int stride = gridDim.x << 2;  // total waves
    float4 bb = ((const float4*)bs)[c4];

    int nodeA = wid;
    int sA = 0, eA = 0;
    if (nodeA < n) { sA = rowstart[nodeA]; eA = rowend[nodeA]; }
    int nodeB = nodeA + stride;
    int sB = 0, eB = 0;
    if (nodeB < n) { sB = rowstart[nodeB]; eB = rowend[nodeB]; }
    int sregA = 0; uint2 uzA = make_uint2(0u, 0u); float diA = 0.f;
    if (nodeA < n) {
        int c0 = min(eA - sA, 64);
        if (lane < c0) sregA = csr[sA + lane];
        uzA = *(const uint2*)&zbf[(size_t)nodeA * D + 4 * c4];
        diA = dinv[nodeA];
    }

    while (nodeA < n) {
        // prefetch node B's csr slice + epilogue operands (bounds ready)
        int sregB = 0; uint2 uzB = make_uint2(0u, 0u); float diB = 0.f;
        if (nodeB < n) {
            int c0 = min(eB - sB, 64);
            if (lane < c0) sregB = csr[sB + lane];
            uzB = *(const uint2*)&zbf[(size_t)nodeB * D + 4 * c4];
            diB = dinv[nodeB];
        }
        // prefetch node C's bounds
        int nodeC = nodeB + stride;
        int sC = 0, eC = 0;
        if (nodeC < n) { sC = rowstart[nodeC]; eC = rowend[nodeC]; }

        // ---- sum node A ----
        float a0 = 0.f, a1 = 0.f, a2 = 0.f, a3 = 0.f;
        int e = sA;
        bool first = true;
        while (e < eA) {
            int cnt = min(eA - e, 64);
            int sreg = sregA;
            if (!first) sreg = (lane < cnt) ? csr[e + lane] : 0;
            first = false;
            int k = 0;
            for (; k + 15 < cnt; k += 16) {  // 4 loads/group, 16 rows/wave in flight
                int p0 = __shfl(sreg, k + qg);
                int p1 = __shfl(sreg, k + 4 + qg);
                int p2 = __shfl(sreg, k + 8 + qg);
                int p3 = __shfl(sreg, k + 12 + qg);
                uint2 u0 = *(const uint2*)&zbf[(size_t)p0 * D + 4 * c4];
                uint2 u1 = *(const uint2*)&zbf[(size_t)p1 * D + 4 * c4];
                uint2 u2 = *(const uint2*)&zbf[(size_t)p2 * D + 4 * c4];
                uint2 u3 = *(const uint2*)&zbf[(size_t)p3 * D + 4 * c4];
                a0 += bflo(u0.x); a1 += bfhi(u0.x); a2 += bflo(u0.y); a3 += bfhi(u0.y);
                a0 += bflo(u1.x); a1 += bfhi(u1.x); a2 += bflo(u1.y); a3 += bfhi(u1.y);
                a0 += bflo(u2.x); a1 += bfhi(u2.x); a2 += bflo(u2.y); a3 += bfhi(u2.y);
                a0 += bflo(u3.x); a1 += bfhi(u3.x); a2 += bflo(u3.y); a3 += bfhi(u3.y);
            }
            for (; k + 7 < cnt; k += 8) {
                int p0 = __shfl(sreg, k + qg);
                int p1 = __shfl(sreg, k + 4 + qg);
                uint2 u0 = *(const uint2*)&zbf[(size_t)p0 * D + 4 * c4];
                uint2 u1 = *(const uint2*)&zbf[(size_t)p1 * D + 4 * c4];
                a0 += bflo(u0.x); a1 += bfhi(u0.x); a2 += bflo(u0.y); a3 += bfhi(u0.y);
                a0 += bflo(u1.x); a1 += bfhi(u1.x); a2 += bflo(u1.y); a3 += bfhi(u1.y);
            }
            for (; k + 3 < cnt; k += 4) {
                int p0 = __shfl(sreg, k + qg);
                uint2 u0 = *(const uint2*)&zbf[(size_t)p0 * D + 4 * c4];
                a0 += bflo(u0.x); a1 += bfhi(u0.x); a2 += bflo(u0.y); a3 += bfhi(u0.y);
            }
            int r = cnt - k;
            if (r) {  // 1..3 leftover edges; r is wave-uniform -> full exec.
                // shfl+load at full exec with clamped source lane (all source
                // lanes k..k+r-1 are active); accumulate predicated only.
                int p0 = __shfl(sreg, k + (qg < r ? qg : 0));
                uint2 u0 = *(const uint2*)&zbf[(size_t)p0 * D + 4 * c4];
                if (qg < r) {
                    a0 += bflo(u0.x); a1 += bfhi(u0.x);
                    a2 += bflo(u0.y); a3 += bfhi(u0.y);
                }
            }
            e += cnt;
        }
        // reduce across 4 groups
        a0 += __shfl_xor(a0, 16); a1 += __shfl_xor(a1, 16);
        a2 += __shfl_xor(a2, 16); a3 += __shfl_xor(a3, 16);
        a0 += __shfl_xor(a0, 32); a1 += __shfl_xor(a1, 32);
        a2 += __shfl_xor(a2, 32); a3 += __shfl_xor(a3, 32);
        if (lane < 16) {
            float4 o;
            o.x = diA * (a0 + bflo(uzA.x)) + bb.x;
            o.y = diA * (a1 + bfhi(uzA.x)) + bb.y;
            o.z = diA * (a2 + bflo(uzA.y)) + bb.z;
            o.w = diA * (a3 + bfhi(uzA.y)) + bb.w;
            *(float4*)&out[(size_t)nodeA * D + 4 * c4] = o;
        }
        // rotate pipeline
        nodeA = nodeB; sA = sB; eA = eB; sregA = sregB; uzA = uzB; diA = diB;
        nodeB = nodeC; sB = sC; eB = eC;
    }
}

extern "C" void kernel_launch(void* const* d_in, const int* in_sizes, int n_in,
                              void* d_out, int out_size, void* d_ws, size_t ws_size,
                              hipStream_t stream) {
    const float* x = (const float*)d_in[0];
    const int* ei = (const int*)d_in[1];
    const float* W = (const float*)d_in[2];
    const float* b = (const float*)d_in[3];
    const float* A = (const float*)d_in[4];

    const int N = in_sizes[0] / D;
    const int E = in_sizes[1] / 2;
    const int* src = ei;
    const int* dst = ei + E;
    const int NBUCK = (N + BNODES - 1) >> BSHIFT;  // 1563; must be <=2048

    char* ws = (char*)d_ws;
    size_t off = 0;
    auto alloc = [&](size_t bytes) -> char* {
        char* p = ws + off;
        off = (off + bytes + 255) & ~(size_t)255;
        return p;
    };
    int* cursor = (int*)alloc((size_t)NBUCK * 4);
    float* dinv = (float*)alloc((size_t)N * 4);
    float* M = (float*)alloc((size_t)D * D * 4);
    float* bs = (float*)alloc((size_t)D * 4);
    int* binned = (int*)alloc((size_t)NBUCK * ARENA_CAP * 4);  // 10.8 MB arena
    int* rowstart = (int*)alloc((size_t)N * 4);
    int* rowend = (int*)alloc((size_t)N * 4);
    unsigned short* zbf = (unsigned short*)alloc((size_t)N * D * 2);
    (void)ws_size;  // total ~25 MiB (< 32.06 MiB proven safe)

    prep_kernel<<<16, 256, 0, stream>>>(W, b, A, M, bs, cursor, NBUCK);
    bin_kernel<<<(E + BIN_TILE - 1) / BIN_TILE, 512, 0, stream>>>(src, dst, cursor, binned, E);
    sort_kernel<<<NBUCK, 256, 0, stream>>>(binned, cursor, rowstart, rowend, dinv, N);
    zmat_kernel<<<(N + 63) >> 6, 256, 0, stream>>>(x, M, dinv, zbf, N);
    gather_kernel<<<2048, 256, 0, stream>>>(zbf, binned, rowstart, rowend, dinv, bs, (float*)d_out, N);
}